// Round 8
// baseline (484.159 us; speedup 1.0000x reference)
//
#include <hip/hip_runtime.h>

typedef unsigned short ushort_t;
typedef __attribute__((ext_vector_type(8))) __bf16 bf16x8;
typedef __attribute__((ext_vector_type(4))) float f32x4;

#define SEQ 8192
#define DIN 1024
#define DOUT 1024

// epilogue output modes
#define OM_BF16 0
#define OM_F32  1
#define OM_EXP  2   // bf16 exp2(scale*acc) store + per-block partial row-sums -> rsp
#define OM_NORM 3   // f32 store of acc * invrs[row] (precomputed 1/rowsum)

#if defined(__has_builtin)
#if __has_builtin(__builtin_amdgcn_cvt_pk_bf16_f32)
#define HAVE_PK_BF16 1
#endif
#endif
#ifndef HAVE_PK_BF16
#define HAVE_PK_BF16 0
#endif

__device__ __forceinline__ ushort_t f2bf(float f) {
  union { float f; unsigned u; } c; c.f = f;
  unsigned u = c.u;
  return (ushort_t)((u + 0x7fffu + ((u >> 16) & 1u)) >> 16);  // RNE
}

// pack two f32 -> two bf16 in one VGPR (v_cvt_pk_bf16_f32 when available)
__device__ __forceinline__ unsigned pk_bf16(float a, float b) {
#if HAVE_PK_BF16
  auto r = __builtin_amdgcn_cvt_pk_bf16_f32(a, b);
  unsigned u;
  __builtin_memcpy(&u, &r, 4);
  return u;
#else
  return (unsigned)f2bf(a) | ((unsigned)f2bf(b) << 16);
#endif
}

__device__ __forceinline__ void async16(ushort_t* lds, const ushort_t* g) {
  __builtin_amdgcn_global_load_lds(
      (__attribute__((address_space(1))) void*)g,
      (__attribute__((address_space(3))) void*)lds, 16, 0, 0);
}

// ------- fused fp32 -> bf16 convert for x, Wq, Wk, Wv -------
__global__ __launch_bounds__(256) void cvt_all_kernel(
    const float* __restrict__ x, const float* __restrict__ wq,
    const float* __restrict__ wk, const float* __restrict__ wv,
    ushort_t* __restrict__ xb, ushort_t* __restrict__ wqkb,
    ushort_t* __restrict__ wvb) {
  int b = blockIdx.x;
  const float* src;
  ushort_t* dst;
  int idx;
  if (b < 8192) {
    src = x; dst = xb; idx = b * 256 + threadIdx.x;
  } else {
    int r = b - 8192;
    int w = r >> 10;
    idx = (r & 1023) * 256 + threadIdx.x;
    if (w == 0)      { src = wq; dst = wqkb; }
    else if (w == 1) { src = wk; dst = wqkb + DOUT * DIN; }
    else             { src = wv; dst = wvb; }
  }
  float4 f = ((const float4*)src)[idx];
  unsigned u01 = pk_bf16(f.x, f.y);
  unsigned u23 = pk_bf16(f.z, f.w);
  uint2 o; o.x = u01; o.y = u23;
  ((uint2*)dst)[idx] = o;
}

// ------- rowsum partials [64][SEQ] -> invrs[SEQ] = 1/sum -------
__global__ __launch_bounds__(256) void rowsum_inv_kernel(const float* __restrict__ rsp,
                                                         float* __restrict__ invrs) {
  int r = blockIdx.x * 256 + threadIdx.x;
  float s = 0.f;
  #pragma unroll
  for (int p2 = 0; p2 < 64; ++p2) s += rsp[p2 * SEQ + r];
  invrs[r] = 1.0f / s;
}

// ---------------- GEMM body: C[M][N] = A[M][K] @ B[N][K]^T ----------------
// 128x128 tile, templated BK (64/128), 4 waves (2x2), each wave 64x64 via 4x4
// mfma_f32_16x16x32_bf16. Round-5 proven layout: XOR-swizzled row-major LDS
// (16B chunk low3 ^ row&7) — conflict-free ds_read_b128, swizzle on the GLOBAL
// source address so global_load_lds lane-contiguity holds and the wave's
// global accesses stay in contiguous row segments (round-6 lesson: never
// scatter the global side — 2x regression).
// OM_EXP: store exp2(scale*acc) bf16 (scale carries log2e); partial row-sums
//   via shuffle+LDS, PLAIN store to rsp[nt][row] (no atomics: round-4 showed
//   1M atomicAdds onto 8K addresses = ~40 us stall).
// OM_NORM: normalize by precomputed invrs[row] (tiny separate kernel).
// bf16 epilogues use v_cvt_pk_bf16_f32 (round-8: manual f2bf was 4 VALU
// ops/elem — the S-gemm epilogue was the +25 us over the plateau floor).
template <int OUTMODE, int BK>
__device__ __forceinline__ void gemm_body(const ushort_t* __restrict__ A,
                                          const ushort_t* __restrict__ B,
                                          void* __restrict__ C,
                                          int lda, int ldb, int ldc,
                                          int K, float scale,
                                          float* __restrict__ rsp,
                                          const float* __restrict__ invrs,
                                          int mt, int nt,
                                          ushort_t* As, ushort_t* Bs) {
  constexpr int CPR = BK / 8;           // 16B chunks per row
  constexpr int NI = BK / 16;           // staging chunks per thread
  const int t = threadIdx.x;
  const int lane = t & 63;
  const int wave = t >> 6;
  const int wr = wave >> 1, wc = wave & 1;
  const int quad = lane >> 4, r16 = lane & 15;

  const int rowBase = mt * 128;
  const int colBase = nt * 128;

  // per-thread 32-bit staging offsets (elements), bumped by BK per kt
  unsigned offA[NI], offB[NI];
  #pragma unroll
  for (int i = 0; i < NI; ++i) {
    int c = t + i * 256;
    int row = c / CPR;
    int kq = c & (CPR - 1);
    int kqs = (kq & ~7) | ((kq & 7) ^ (row & 7));
    offA[i] = (unsigned)((rowBase + row) * lda + kqs * 8);
    offB[i] = (unsigned)((colBase + row) * ldb + kqs * 8);
  }

  f32x4 acc[4][4] = {};

  const int nk = K / BK;
  for (int kt = 0; kt < nk; ++kt) {
    #pragma unroll
    for (int i = 0; i < NI; ++i) {
      async16(&As[(t + i * 256) * 8], A + offA[i]); offA[i] += BK;
      async16(&Bs[(t + i * 256) * 8], B + offB[i]); offB[i] += BK;
    }
    __syncthreads();
    #pragma unroll
    for (int ks = 0; ks < BK / 32; ++ks) {
      bf16x8 af[4], bfr[4];
      #pragma unroll
      for (int mi = 0; mi < 4; ++mi) {
        int row = wr * 64 + mi * 16 + r16;
        int kq = ks * 4 + quad;
        int c = row * CPR + ((kq & ~7) | ((kq & 7) ^ (row & 7)));
        af[mi] = *(const bf16x8*)&As[c * 8];
      }
      #pragma unroll
      for (int ni = 0; ni < 4; ++ni) {
        int row = wc * 64 + ni * 16 + r16;
        int kq = ks * 4 + quad;
        int c = row * CPR + ((kq & ~7) | ((kq & 7) ^ (row & 7)));
        bfr[ni] = *(const bf16x8*)&Bs[c * 8];
      }
      #pragma unroll
      for (int mi = 0; mi < 4; ++mi)
        #pragma unroll
        for (int ni = 0; ni < 4; ++ni)
          acc[mi][ni] = __builtin_amdgcn_mfma_f32_16x16x32_bf16(af[mi], bfr[ni],
                                                                acc[mi][ni], 0, 0, 0);
    }
    __syncthreads();
  }

  // ---- epilogue: C/D layout col=lane&15, row=quad*4+reg ----
  float iv[4][4];
  if (OUTMODE == OM_NORM) {
    #pragma unroll
    for (int mi = 0; mi < 4; ++mi)
      #pragma unroll
      for (int r = 0; r < 4; ++r)
        iv[mi][r] = invrs[rowBase + wr * 64 + mi * 16 + quad * 4 + r];
  }

  float psum[4][4];
  if (OUTMODE == OM_EXP) {
    #pragma unroll
    for (int mi = 0; mi < 4; ++mi)
      #pragma unroll
      for (int r = 0; r < 4; ++r) psum[mi][r] = 0.f;
  }

  #pragma unroll
  for (int mi = 0; mi < 4; ++mi)
    #pragma unroll
    for (int r = 0; r < 4; ++r) {
      int grow = rowBase + wr * 64 + mi * 16 + quad * 4 + r;
      if (OUTMODE == OM_F32 || OUTMODE == OM_NORM) {
        float m = (OUTMODE == OM_NORM) ? iv[mi][r] : scale;
        #pragma unroll
        for (int ni = 0; ni < 4; ++ni) {
          int gcol = colBase + wc * 64 + ni * 16 + r16;
          ((float*)C)[(size_t)grow * ldc + gcol] = acc[mi][ni][r] * m;
        }
      } else {
        float e[4];
        #pragma unroll
        for (int ni = 0; ni < 4; ++ni) {
          float a = acc[mi][ni][r] * scale;
          if (OUTMODE == OM_EXP) { a = exp2f(a); psum[mi][r] += a; }
          e[ni] = a;
        }
        unsigned u01 = pk_bf16(e[0], e[1]);
        unsigned u23 = pk_bf16(e[2], e[3]);
        ushort_t* cp = (ushort_t*)C + (size_t)grow * ldc + colBase + wc * 64 + r16;
        cp[0]  = (ushort_t)u01;
        cp[16] = (ushort_t)(u01 >> 16);   // global_store_short_d16_hi
        cp[32] = (ushort_t)u23;
        cp[48] = (ushort_t)(u23 >> 16);
      }
    }

  if (OUTMODE == OM_EXP) {
    // 16-lane shuffle reduce -> lane r16==0 holds this wave's 64-col partial
    float* lds_rs = (float*)As;  // [2][128], LDS dead after final barrier
    #pragma unroll
    for (int mi = 0; mi < 4; ++mi)
      #pragma unroll
      for (int r = 0; r < 4; ++r) {
        float s = psum[mi][r];
        s += __shfl_xor(s, 1, 64);
        s += __shfl_xor(s, 2, 64);
        s += __shfl_xor(s, 4, 64);
        s += __shfl_xor(s, 8, 64);
        if (r16 == 0)
          lds_rs[wc * 128 + wr * 64 + mi * 16 + quad * 4 + r] = s;
      }
    __syncthreads();
    if (t < 128)
      rsp[(size_t)nt * SEQ + rowBase + t] = lds_rs[t] + lds_rs[128 + t];
  }
}

// S-gemm / PV wrapper. SWZ=1: 8 blocks sharing an A-strip on one XCD (4x FETCH cut).
template <int OUTMODE, int SWZ, int BK>
__global__ __launch_bounds__(256) void gemm_bt(const ushort_t* __restrict__ A,
                                               const ushort_t* __restrict__ B,
                                               void* __restrict__ C,
                                               int lda, int ldb, int ldc,
                                               int K, float scale,
                                               float* __restrict__ rsp,
                                               const float* __restrict__ invrs) {
  __shared__ ushort_t As[128 * BK];
  __shared__ ushort_t Bs[128 * BK];
  int mt, nt;
  if (SWZ == 1) {
    mt = blockIdx.x * (gridDim.y >> 3) + (blockIdx.y >> 3);
    nt = blockIdx.y & 7;
  } else {
    mt = blockIdx.y;
    nt = blockIdx.x;
  }
  gemm_body<OUTMODE, BK>(A, B, C, lda, ldb, ldc, K, scale, rsp, invrs, mt, nt, As, Bs);
}

// merged qk-proj + vT-proj: blocks [0,1024) do [q|k] = x @ [Wq|Wk]^T tiles,
// blocks [1024,1536) do v^T = Wv @ x^T tiles. One launch: kills a gap and
// overlaps qk's tail with vT. Merged grid isn't grid-limited -> BK=64 both.
__global__ __launch_bounds__(256) void proj_fused_kernel(
    const ushort_t* __restrict__ xb, const ushort_t* __restrict__ wqkb,
    const ushort_t* __restrict__ wvb, ushort_t* __restrict__ qkb,
    ushort_t* __restrict__ vtb) {
  __shared__ ushort_t As[128 * 64];
  __shared__ ushort_t Bs[128 * 64];
  int b = blockIdx.x;
  const ushort_t *A, *B;
  ushort_t* C;
  int ldc, mt, nt;
  if (b < 1024) {          // qk: M=8192, N=2048 (grid was 16 x 64, x-fastest)
    A = xb; B = wqkb; C = qkb; ldc = 2 * DOUT;
    mt = b >> 4; nt = b & 15;
  } else {                 // vT: M=1024, N=8192 (grid was 64 x 8, x-fastest)
    int b2 = b - 1024;
    A = wvb; B = xb; C = vtb; ldc = SEQ;
    mt = b2 >> 6; nt = b2 & 63;
  }
  gemm_body<OM_BF16, 64>(A, B, C, DIN, DIN, ldc, DIN, 1.0f, nullptr, nullptr,
                         mt, nt, As, Bs);
}

extern "C" void kernel_launch(void* const* d_in, const int* in_sizes, int n_in,
                              void* d_out, int out_size, void* d_ws, size_t ws_size,
                              hipStream_t stream) {
  const float* x  = (const float*)d_in[0];
  const float* Wq = (const float*)d_in[1];
  const float* Wk = (const float*)d_in[2];
  const float* Wv = (const float*)d_in[3];
  float* out = (float*)d_out;

  char* p = (char*)d_ws;
  ushort_t* xb   = (ushort_t*)p; p += (size_t)SEQ * DIN * 2;        // 16 MB
  ushort_t* wqkb = (ushort_t*)p; p += (size_t)2 * DOUT * DIN * 2;   //  4 MB (Wq|Wk)
  ushort_t* wvb  = (ushort_t*)p; p += (size_t)DOUT * DIN * 2;       //  2 MB
  ushort_t* qkb  = (ushort_t*)p; p += (size_t)SEQ * 2 * DOUT * 2;   // 32 MB ([S][2048], q|k)
  ushort_t* vtb  = (ushort_t*)p; p += (size_t)DOUT * SEQ * 2;       // 16 MB (v^T)
  float*    rsp  = (float*)p;    p += (size_t)64 * SEQ * 4;         //  2 MB partial rowsums
  float*    irs  = (float*)p;    p += (size_t)SEQ * 4;              // 32 KB 1/rowsum
  ushort_t* Sb   = (ushort_t*)p; p += (size_t)SEQ * SEQ * 2;        // 128 MB

  // fp32 -> bf16 for all four tensors (one launch)
  cvt_all_kernel<<<8192 + 3 * 1024, 256, 0, stream>>>(x, Wq, Wk, Wv, xb, wqkb, wvb);

  dim3 blk(256);
  // [q|k] = x @ [Wq|Wk]^T and v^T = Wv @ x^T in one dispatch
  proj_fused_kernel<<<1536, blk, 0, stream>>>(xb, wqkb, wvb, qkb, vtb);

  // E = exp((q @ k^T)/32) via exp2, partial row sums -> rsp : M=N=8192, K=1024
  gemm_bt<OM_EXP, 0, 64><<<dim3(SEQ / 128, SEQ / 128), blk, 0, stream>>>(
      qkb, qkb + DOUT, Sb, 2 * DOUT, 2 * DOUT, SEQ, DIN,
      0.03125f * 1.44269504f, rsp, nullptr);

  // invrs[r] = 1 / sum_p rsp[p][r]
  rowsum_inv_kernel<<<SEQ / 256, blk, 0, stream>>>(rsp, irs);

  // out = (E @ v) * invrs : M=8192, N=1024, K=8192, fp32 out, XCD-swizzled, BK=128
  gemm_bt<OM_NORM, 1, 128><<<dim3(DOUT / 128, SEQ / 128), blk, 0, stream>>>(
      Sb, vtb, out, SEQ, SEQ, DOUT, SEQ, 1.0f, nullptr, irs);
}

// Round 9
// 479.355 us; speedup vs baseline: 1.0100x; 1.0100x over previous
//
#include <hip/hip_runtime.h>

typedef unsigned short ushort_t;
typedef __attribute__((ext_vector_type(8))) __bf16 bf16x8;
typedef __attribute__((ext_vector_type(4))) float f32x4;

#define SEQ 8192
#define DIN 1024
#define DOUT 1024

// epilogue output modes
#define OM_BF16 0
#define OM_F32  1
#define OM_EXP  2   // bf16 exp2(scale*acc) store + per-block partial row-sums -> rsp
#define OM_NORM 3   // f32 store of acc * invrs[row] (precomputed 1/rowsum)

#if defined(__has_builtin)
#if __has_builtin(__builtin_amdgcn_cvt_pk_bf16_f32)
#define HAVE_PK_BF16 1
#endif
#if __has_builtin(__builtin_amdgcn_exp2f)
#define HAVE_EXP2 1
#endif
#endif
#ifndef HAVE_PK_BF16
#define HAVE_PK_BF16 0
#endif
#ifndef HAVE_EXP2
#define HAVE_EXP2 0
#endif

// raw v_exp_f32 — exp2f() without fast-math lowers to the precise libm
// sequence (~10-20 VALU ops: clamp/denormal paths). Our args are in
// [-0.37,0.37] so the raw instruction is exact enough. (round-9 theory: this
// libm blob is the S-gemm's +20us of epilogue VALU.)
__device__ __forceinline__ float fast_exp2(float x) {
#if HAVE_EXP2
  return __builtin_amdgcn_exp2f(x);
#else
  return exp2f(x);
#endif
}

__device__ __forceinline__ ushort_t f2bf(float f) {
  union { float f; unsigned u; } c; c.f = f;
  unsigned u = c.u;
  return (ushort_t)((u + 0x7fffu + ((u >> 16) & 1u)) >> 16);  // RNE
}

// pack two f32 -> two bf16 in one VGPR (v_cvt_pk_bf16_f32 when available)
__device__ __forceinline__ unsigned pk_bf16(float a, float b) {
#if HAVE_PK_BF16
  auto r = __builtin_amdgcn_cvt_pk_bf16_f32(a, b);
  unsigned u;
  __builtin_memcpy(&u, &r, 4);
  return u;
#else
  return (unsigned)f2bf(a) | ((unsigned)f2bf(b) << 16);
#endif
}

__device__ __forceinline__ void async16(ushort_t* lds, const ushort_t* g) {
  __builtin_amdgcn_global_load_lds(
      (__attribute__((address_space(1))) void*)g,
      (__attribute__((address_space(3))) void*)lds, 16, 0, 0);
}

// ------- fused fp32 -> bf16 convert for x, Wq, Wk, Wv -------
__global__ __launch_bounds__(256) void cvt_all_kernel(
    const float* __restrict__ x, const float* __restrict__ wq,
    const float* __restrict__ wk, const float* __restrict__ wv,
    ushort_t* __restrict__ xb, ushort_t* __restrict__ wqkb,
    ushort_t* __restrict__ wvb) {
  int b = blockIdx.x;
  const float* src;
  ushort_t* dst;
  int idx;
  if (b < 8192) {
    src = x; dst = xb; idx = b * 256 + threadIdx.x;
  } else {
    int r = b - 8192;
    int w = r >> 10;
    idx = (r & 1023) * 256 + threadIdx.x;
    if (w == 0)      { src = wq; dst = wqkb; }
    else if (w == 1) { src = wk; dst = wqkb + DOUT * DIN; }
    else             { src = wv; dst = wvb; }
  }
  float4 f = ((const float4*)src)[idx];
  unsigned u01 = pk_bf16(f.x, f.y);
  unsigned u23 = pk_bf16(f.z, f.w);
  uint2 o; o.x = u01; o.y = u23;
  ((uint2*)dst)[idx] = o;
}

// ------- rowsum partials [64][SEQ] -> invrs[SEQ] = 1/sum -------
__global__ __launch_bounds__(256) void rowsum_inv_kernel(const float* __restrict__ rsp,
                                                         float* __restrict__ invrs) {
  int r = blockIdx.x * 256 + threadIdx.x;
  float s = 0.f;
  #pragma unroll
  for (int p2 = 0; p2 < 64; ++p2) s += rsp[p2 * SEQ + r];
  invrs[r] = 1.0f / s;
}

// ---------------- GEMM body: C[M][N] = A[M][K] @ B[N][K]^T ----------------
// 128x128 tile, templated BK (64/128), 4 waves (2x2), each wave 64x64 via 4x4
// mfma_f32_16x16x32_bf16. Round-5 proven layout: XOR-swizzled row-major LDS
// (16B chunk low3 ^ row&7) — conflict-free ds_read_b128, swizzle on the GLOBAL
// source address so global_load_lds lane-contiguity holds and the wave's
// global accesses stay in contiguous row segments (round-6 lesson: never
// scatter the global side — 2x regression).
// OM_EXP: store exp2(scale*acc) bf16 (scale carries log2e) via raw v_exp_f32;
//   partial row-sums via shuffle+LDS, PLAIN store to rsp[nt][row] (no atomics:
//   round-4 showed 1M atomicAdds onto 8K addresses = ~40 us stall).
// OM_NORM: normalize by precomputed invrs[row] (tiny separate kernel).
template <int OUTMODE, int BK>
__device__ __forceinline__ void gemm_body(const ushort_t* __restrict__ A,
                                          const ushort_t* __restrict__ B,
                                          void* __restrict__ C,
                                          int lda, int ldb, int ldc,
                                          int K, float scale,
                                          float* __restrict__ rsp,
                                          const float* __restrict__ invrs,
                                          int mt, int nt,
                                          ushort_t* As, ushort_t* Bs) {
  constexpr int CPR = BK / 8;           // 16B chunks per row
  constexpr int NI = BK / 16;           // staging chunks per thread
  const int t = threadIdx.x;
  const int lane = t & 63;
  const int wave = t >> 6;
  const int wr = wave >> 1, wc = wave & 1;
  const int quad = lane >> 4, r16 = lane & 15;

  const int rowBase = mt * 128;
  const int colBase = nt * 128;

  // per-thread 32-bit staging offsets (elements), bumped by BK per kt
  unsigned offA[NI], offB[NI];
  #pragma unroll
  for (int i = 0; i < NI; ++i) {
    int c = t + i * 256;
    int row = c / CPR;
    int kq = c & (CPR - 1);
    int kqs = (kq & ~7) | ((kq & 7) ^ (row & 7));
    offA[i] = (unsigned)((rowBase + row) * lda + kqs * 8);
    offB[i] = (unsigned)((colBase + row) * ldb + kqs * 8);
  }

  f32x4 acc[4][4] = {};

  const int nk = K / BK;
  for (int kt = 0; kt < nk; ++kt) {
    #pragma unroll
    for (int i = 0; i < NI; ++i) {
      async16(&As[(t + i * 256) * 8], A + offA[i]); offA[i] += BK;
      async16(&Bs[(t + i * 256) * 8], B + offB[i]); offB[i] += BK;
    }
    __syncthreads();
    #pragma unroll
    for (int ks = 0; ks < BK / 32; ++ks) {
      bf16x8 af[4], bfr[4];
      #pragma unroll
      for (int mi = 0; mi < 4; ++mi) {
        int row = wr * 64 + mi * 16 + r16;
        int kq = ks * 4 + quad;
        int c = row * CPR + ((kq & ~7) | ((kq & 7) ^ (row & 7)));
        af[mi] = *(const bf16x8*)&As[c * 8];
      }
      #pragma unroll
      for (int ni = 0; ni < 4; ++ni) {
        int row = wc * 64 + ni * 16 + r16;
        int kq = ks * 4 + quad;
        int c = row * CPR + ((kq & ~7) | ((kq & 7) ^ (row & 7)));
        bfr[ni] = *(const bf16x8*)&Bs[c * 8];
      }
      #pragma unroll
      for (int mi = 0; mi < 4; ++mi)
        #pragma unroll
        for (int ni = 0; ni < 4; ++ni)
          acc[mi][ni] = __builtin_amdgcn_mfma_f32_16x16x32_bf16(af[mi], bfr[ni],
                                                                acc[mi][ni], 0, 0, 0);
    }
    __syncthreads();
  }

  // ---- epilogue: C/D layout col=lane&15, row=quad*4+reg ----
  float iv[4][4];
  if (OUTMODE == OM_NORM) {
    #pragma unroll
    for (int mi = 0; mi < 4; ++mi)
      #pragma unroll
      for (int r = 0; r < 4; ++r)
        iv[mi][r] = invrs[rowBase + wr * 64 + mi * 16 + quad * 4 + r];
  }

  float psum[4][4];
  if (OUTMODE == OM_EXP) {
    #pragma unroll
    for (int mi = 0; mi < 4; ++mi)
      #pragma unroll
      for (int r = 0; r < 4; ++r) psum[mi][r] = 0.f;
  }

  #pragma unroll
  for (int mi = 0; mi < 4; ++mi)
    #pragma unroll
    for (int ni = 0; ni < 4; ++ni)
      #pragma unroll
      for (int r = 0; r < 4; ++r) {
        int grow = rowBase + wr * 64 + mi * 16 + quad * 4 + r;
        int gcol = colBase + wc * 64 + ni * 16 + r16;
        float a = acc[mi][ni][r];
        if (OUTMODE == OM_F32) {
          ((float*)C)[(size_t)grow * ldc + gcol] = a * scale;
        } else if (OUTMODE == OM_BF16) {
          ((ushort_t*)C)[(size_t)grow * ldc + gcol] = f2bf(a * scale);
        } else if (OUTMODE == OM_EXP) {
          float e = fast_exp2(a * scale);   // scale carries the log2(e) factor
          psum[mi][r] += e;
          ((ushort_t*)C)[(size_t)grow * ldc + gcol] = f2bf(e);
        } else {  // OM_NORM
          ((float*)C)[(size_t)grow * ldc + gcol] = a * iv[mi][r];
        }
      }

  if (OUTMODE == OM_EXP) {
    // 16-lane shuffle reduce -> lane r16==0 holds this wave's 64-col partial
    float* lds_rs = (float*)As;  // [2][128], LDS dead after final barrier
    #pragma unroll
    for (int mi = 0; mi < 4; ++mi)
      #pragma unroll
      for (int r = 0; r < 4; ++r) {
        float s = psum[mi][r];
        s += __shfl_xor(s, 1, 64);
        s += __shfl_xor(s, 2, 64);
        s += __shfl_xor(s, 4, 64);
        s += __shfl_xor(s, 8, 64);
        if (r16 == 0)
          lds_rs[wc * 128 + wr * 64 + mi * 16 + quad * 4 + r] = s;
      }
    __syncthreads();
    if (t < 128)
      rsp[(size_t)nt * SEQ + rowBase + t] = lds_rs[t] + lds_rs[128 + t];
  }
}

// S-gemm / PV wrapper. SWZ=1: 8 blocks sharing an A-strip on one XCD (4x FETCH cut).
template <int OUTMODE, int SWZ, int BK>
__global__ __launch_bounds__(256) void gemm_bt(const ushort_t* __restrict__ A,
                                               const ushort_t* __restrict__ B,
                                               void* __restrict__ C,
                                               int lda, int ldb, int ldc,
                                               int K, float scale,
                                               float* __restrict__ rsp,
                                               const float* __restrict__ invrs) {
  __shared__ ushort_t As[128 * BK];
  __shared__ ushort_t Bs[128 * BK];
  int mt, nt;
  if (SWZ == 1) {
    mt = blockIdx.x * (gridDim.y >> 3) + (blockIdx.y >> 3);
    nt = blockIdx.y & 7;
  } else {
    mt = blockIdx.y;
    nt = blockIdx.x;
  }
  gemm_body<OUTMODE, BK>(A, B, C, lda, ldb, ldc, K, scale, rsp, invrs, mt, nt, As, Bs);
}

// merged qk-proj + vT-proj: blocks [0,1024) do [q|k] = x @ [Wq|Wk]^T tiles,
// blocks [1024,1536) do v^T = Wv @ x^T tiles.
__global__ __launch_bounds__(256) void proj_fused_kernel(
    const ushort_t* __restrict__ xb, const ushort_t* __restrict__ wqkb,
    const ushort_t* __restrict__ wvb, ushort_t* __restrict__ qkb,
    ushort_t* __restrict__ vtb) {
  __shared__ ushort_t As[128 * 64];
  __shared__ ushort_t Bs[128 * 64];
  int b = blockIdx.x;
  const ushort_t *A, *B;
  ushort_t* C;
  int ldc, mt, nt;
  if (b < 1024) {          // qk: M=8192, N=2048
    A = xb; B = wqkb; C = qkb; ldc = 2 * DOUT;
    mt = b >> 4; nt = b & 15;
  } else {                 // vT: M=1024, N=8192
    int b2 = b - 1024;
    A = wvb; B = xb; C = vtb; ldc = SEQ;
    mt = b2 >> 6; nt = b2 & 63;
  }
  gemm_body<OM_BF16, 64>(A, B, C, DIN, DIN, ldc, DIN, 1.0f, nullptr, nullptr,
                         mt, nt, As, Bs);
}

extern "C" void kernel_launch(void* const* d_in, const int* in_sizes, int n_in,
                              void* d_out, int out_size, void* d_ws, size_t ws_size,
                              hipStream_t stream) {
  const float* x  = (const float*)d_in[0];
  const float* Wq = (const float*)d_in[1];
  const float* Wk = (const float*)d_in[2];
  const float* Wv = (const float*)d_in[3];
  float* out = (float*)d_out;

  char* p = (char*)d_ws;
  ushort_t* xb   = (ushort_t*)p; p += (size_t)SEQ * DIN * 2;        // 16 MB
  ushort_t* wqkb = (ushort_t*)p; p += (size_t)2 * DOUT * DIN * 2;   //  4 MB (Wq|Wk)
  ushort_t* wvb  = (ushort_t*)p; p += (size_t)DOUT * DIN * 2;       //  2 MB
  ushort_t* qkb  = (ushort_t*)p; p += (size_t)SEQ * 2 * DOUT * 2;   // 32 MB ([S][2048], q|k)
  ushort_t* vtb  = (ushort_t*)p; p += (size_t)DOUT * SEQ * 2;       // 16 MB (v^T)
  float*    rsp  = (float*)p;    p += (size_t)64 * SEQ * 4;         //  2 MB partial rowsums
  float*    irs  = (float*)p;    p += (size_t)SEQ * 4;              // 32 KB 1/rowsum
  ushort_t* Sb   = (ushort_t*)p; p += (size_t)SEQ * SEQ * 2;        // 128 MB

  // fp32 -> bf16 for all four tensors (one launch)
  cvt_all_kernel<<<8192 + 3 * 1024, 256, 0, stream>>>(x, Wq, Wk, Wv, xb, wqkb, wvb);

  dim3 blk(256);
  // [q|k] = x @ [Wq|Wk]^T and v^T = Wv @ x^T in one dispatch
  proj_fused_kernel<<<1536, blk, 0, stream>>>(xb, wqkb, wvb, qkb, vtb);

  // E = exp((q @ k^T)/32) via raw v_exp_f32, partial row sums -> rsp
  gemm_bt<OM_EXP, 0, 64><<<dim3(SEQ / 128, SEQ / 128), blk, 0, stream>>>(
      qkb, qkb + DOUT, Sb, 2 * DOUT, 2 * DOUT, SEQ, DIN,
      0.03125f * 1.44269504f, rsp, nullptr);

  // invrs[r] = 1 / sum_p rsp[p][r]
  rowsum_inv_kernel<<<SEQ / 256, blk, 0, stream>>>(rsp, irs);

  // out = (E @ v) * invrs : M=8192, N=1024, K=8192, fp32 out, XCD-swizzled, BK=128
  gemm_bt<OM_NORM, 1, 128><<<dim3(DOUT / 128, SEQ / 128), blk, 0, stream>>>(
      Sb, vtb, out, SEQ, SEQ, DOUT, SEQ, 1.0f, nullptr, irs);
}